// Round 16
// baseline (368.293 us; speedup 1.0000x reference)
//
#include <hip/hip_runtime.h>

typedef float f32x4 __attribute__((ext_vector_type(4)));
typedef short s16x8 __attribute__((ext_vector_type(8)));
typedef short s16x4 __attribute__((ext_vector_type(4)));
typedef unsigned u32x4 __attribute__((ext_vector_type(4)));
typedef unsigned u32x2 __attribute__((ext_vector_type(2)));

#define DEVI __device__ __forceinline__

static constexpr int B_ = 4, T_ = 4096, D_ = 2048, E_ = 8, C_ = 512, O_ = 2048, I_ = 256;
static constexpr size_t XDN = (size_t)B_ * E_ * I_ * C_;  // 4,194,304

DEVI short f2bf(float f) {
  unsigned u = __builtin_bit_cast(unsigned, f);
  u += 0x7FFFu + ((u >> 16) & 1u);
  return (short)(u >> 16);
}

// packed f32x2 -> bf16x2 (RNE), one VALU op
DEVI unsigned cvtpk(float lo, float hi) {
  unsigned r;
  asm("v_cvt_pk_bf16_f32 %0, %1, %2" : "=v"(r) : "v"(lo), "v"(hi));
  return r;
}

DEVI void gll16(const short* gsrc, short* ldst) {
  __builtin_amdgcn_global_load_lds(
      (const __attribute__((address_space(1))) void*)gsrc,
      (__attribute__((address_space(3))) void*)ldst, 16, 0, 0);
}

// ---------------------------------------------------------------------------
// Kernel 1 (FUSED): blocks [0,256) = gemm1 split-K=2; blocks [256,1280) =
// wT prep (w[e][o][i] f32 -> wT[o][e*256+i] bf16, pre-swizzled d8blk^(o&7)).
// gemm1: 128(i) x 256(c) tile, 512 thr / 8 waves (2Mx4N), acc[4][4].
// ---------------------------------------------------------------------------
__global__ __launch_bounds__(512, 2) void k_gemm1(const float* __restrict__ x,
                                                  const float* __restrict__ disp,
                                                  const float* __restrict__ w,
                                                  short* __restrict__ wT,
                                                  float* __restrict__ xdP) {
  __shared__ short lXT[128 * 64];  // [i][t] swizzled (16 KB)
  __shared__ short lDT[256 * 64];  // [c][t] swizzled (32 KB)
  const int tid = threadIdx.x;
  const int bid = blockIdx.x;

  if (bid >= 256) {  // ---- prep_wT role ----
    const int pb = bid - 256;
#pragma unroll
    for (int u = 0; u < 2; u++) {
      const int idx = (pb * 512 + tid) * 2 + u;   // [0, 1M)
      const int o = idx >> 9;
      const int dd = (idx & 511) << 2;            // d = e*256+i
      const int e = dd >> 8, i = dd & 255;
      f32x4 v = *(const f32x4*)(w + (((size_t)e * O_ + o) * I_ + i));
      u32x2 p = {cvtpk(v[0], v[1]), cvtpk(v[2], v[3])};
      const int dsw = (dd & ~63) | (dd & 7) | ((((dd >> 3) & 7) ^ (o & 7)) << 3);
      *(u32x2*)(wT + (size_t)o * D_ + dsw) = p;
    }
    return;
  }

  // ---- gemm1 role ----
  const int xcd = bid & 7, slot = bid >> 3;      // slot 0..31
  const int grp = (slot >> 2) * 8 + xcd;         // 0..63 = 32 be x 2 kc
  const int jj = slot & 3;                       // tile within group
  const int be = grp >> 1, kc = grp & 1;
  const int mt = jj >> 1, nt = jj & 1;
  const int b = be >> 3, e = be & 7;
  const int lane = tid & 63, wid = tid >> 6;
  const int wm = wid >> 2, wn = wid & 3;         // 2 x 4 waves
  const int g = lane >> 4, lr = lane & 15;

  const size_t xbase = (size_t)b * T_ * D_ + (size_t)e * I_ + (size_t)mt * 128;
  const size_t dbase = (size_t)b * T_ * (E_ * C_) + (size_t)e * C_ + (size_t)nt * 256;

  const f32x4 z4 = {0.f, 0.f, 0.f, 0.f};
  f32x4 acc[4][4];
#pragma unroll
  for (int i = 0; i < 4; i++)
#pragma unroll
    for (int j = 0; j < 4; j++) acc[i][j] = z4;

  const int xt0 = (tid >> 4) * 2;    // 0..62  (x staging t-pair)
  const int xi8 = (tid & 15) * 8;    // 0..120 (x staging i-chunk)
  const int dt0 = (tid >> 5) * 2;    // 0..30  (disp staging t-pair, + tt*32)
  const int dc8 = (tid & 31) * 8;    // 0..248 (disp staging c-chunk)
  const int q7 = tid & 7;

  f32x4 xa0, xa1, xb0, xb1;
  f32x4 da[2][4];
  auto loadRegs = [&](int kt) {
    const float* sx = x + xbase + (size_t)(kt + xt0) * D_ + xi8;
    xa0 = *(const f32x4*)sx;
    xa1 = *(const f32x4*)(sx + 4);
    xb0 = *(const f32x4*)(sx + D_);
    xb1 = *(const f32x4*)(sx + D_ + 4);
#pragma unroll
    for (int tt = 0; tt < 2; tt++) {
      const float* sd = disp + dbase + (size_t)(kt + tt * 32 + dt0) * (E_ * C_) + dc8;
      da[tt][0] = *(const f32x4*)sd;
      da[tt][1] = *(const f32x4*)(sd + 4);
      da[tt][2] = *(const f32x4*)(sd + E_ * C_);
      da[tt][3] = *(const f32x4*)(sd + E_ * C_ + 4);
    }
  };
  auto writeLds = [&]() {
#pragma unroll
    for (int j = 0; j < 8; j++) {
      const int i = xi8 + j;
      const int ad = i * 64 + (xt0 ^ ((j ^ q7) << 3));
      float va = (j < 4) ? xa0[j] : xa1[j - 4];
      float vb = (j < 4) ? xb0[j] : xb1[j - 4];
      *(unsigned*)&lXT[ad] = cvtpk(va, vb);
    }
#pragma unroll
    for (int tt = 0; tt < 2; tt++)
#pragma unroll
      for (int j = 0; j < 8; j++) {
        const int c = dc8 + j;
        const int ad = c * 64 + ((tt * 32 + dt0) ^ ((j ^ q7) << 3));
        float ua = (j < 4) ? da[tt][0][j] : da[tt][1][j - 4];
        float ub = (j < 4) ? da[tt][2][j] : da[tt][3][j - 4];
        *(unsigned*)&lDT[ad] = cvtpk(ua, ub);
      }
  };

  const int k0 = kc * 2048, kend = k0 + 2048;
  loadRegs(k0);
  for (int kt = k0; kt < kend; kt += 64) {
    __syncthreads();
    writeLds();
    if (kt + 64 < kend) loadRegs(kt + 64);
    __syncthreads();
#pragma unroll
    for (int kk = 0; kk < 2; kk++) {
      const int tb = kk * 32 + g * 8;
      s16x8 af[4], bfr[4];
#pragma unroll
      for (int mi = 0; mi < 4; mi++) {
        const int r = wm * 64 + mi * 16 + lr;
        const int sws = (((r & 7) ^ ((r >> 3) & 7)) << 3);
        af[mi] = *(const s16x8*)&lXT[r * 64 + (tb ^ sws)];
      }
#pragma unroll
      for (int ni = 0; ni < 4; ni++) {
        const int r = wn * 64 + ni * 16 + lr;
        const int sws = (((r & 7) ^ ((r >> 3) & 7)) << 3);
        bfr[ni] = *(const s16x8*)&lDT[r * 64 + (tb ^ sws)];
      }
#pragma unroll
      for (int mi = 0; mi < 4; mi++)
#pragma unroll
        for (int ni = 0; ni < 4; ni++)
          acc[mi][ni] = __builtin_amdgcn_mfma_f32_16x16x32_bf16(af[mi], bfr[ni], acc[mi][ni], 0, 0, 0);
    }
  }

  float* op = xdP + (size_t)kc * XDN + (size_t)be * I_ * C_;
#pragma unroll
  for (int mi = 0; mi < 4; mi++)
#pragma unroll
    for (int ni = 0; ni < 4; ni++)
#pragma unroll
      for (int r = 0; r < 4; r++) {
        const int ig = mt * 128 + wm * 64 + mi * 16 + g * 4 + r;
        const int cg = nt * 256 + wn * 64 + ni * 16 + lr;
        op[(size_t)ig * C_ + cg] = acc[mi][ni][r];
      }
}

// ---------------------------------------------------------------------------
// Kernel 1b: xdT = bf16(P0 + P1)   (4M elements; split-K reducer)
// ---------------------------------------------------------------------------
__global__ __launch_bounds__(256) void k_cvt(const float* __restrict__ xdP,
                                             short* __restrict__ xdT) {
  size_t idx = (size_t)blockIdx.x * 256 + threadIdx.x;
  f32x4 a = *(const f32x4*)(xdP + idx * 4);
  f32x4 b = *(const f32x4*)(xdP + XDN + idx * 4);
#pragma unroll
  for (int j = 0; j < 4; j++) a[j] += b[j];
  u32x2 p = {cvtpk(a[0], a[1]), cvtpk(a[2], a[3])};
  *(u32x2*)(xdT + idx * 4) = p;
}

// ---------------------------------------------------------------------------
// Kernel 2: z[b][t][d'] = sum_c comb[b,t,e,c]*xdT[b,e][i][c] (bf16)
// 128(t) x 256(i full-I) tile; comb read once. Se by every block.
// z PRE-SWIZZLED (d8blk ^ (t&7)). Grid 1024 = 32 be x 32 mt.
// ---------------------------------------------------------------------------
__global__ __launch_bounds__(512, 2) void k_zgemm(const float* __restrict__ comb,
                                                  const short* __restrict__ xdT,
                                                  short* __restrict__ z,
                                                  float* __restrict__ Se) {
  __shared__ short lA[128 * 64];   // [t][c] swizzled (16 KB)
  __shared__ short lB[256 * 64];   // [i][c] swizzled (32 KB)
  const int tid = threadIdx.x;
  const int bid = blockIdx.x;
  const int be = bid >> 5, mt = bid & 31;
  const int b = be >> 3, e = be & 7;
  const int lane = tid & 63, wid = tid >> 6;
  const int wm = wid >> 2, wn = wid & 3;         // 2 x 4 waves
  const int g = lane >> 4, lr = lane & 15;

  const size_t abase = (size_t)b * T_ * (E_ * C_) + (size_t)(mt * 128) * (E_ * C_) + (size_t)e * C_;
  const short* Bsrc = xdT + (size_t)be * I_ * C_;

  float rs[2] = {0.f, 0.f};
  const f32x4 z4 = {0.f, 0.f, 0.f, 0.f};
  f32x4 acc[4][4];
#pragma unroll
  for (int i = 0; i < 4; i++)
#pragma unroll
    for (int j = 0; j < 4; j++) acc[i][j] = z4;

  for (int ct = 0; ct < C_; ct += 64) {
    __syncthreads();
#pragma unroll
    for (int cc = 0; cc < 2; cc++) {           // A: 128 rows x 64 c
      const int q = tid + 512 * cc;
      const int row = q >> 3;                  // 0..127
      const int k8 = (q & 7) << 3;
      const int sw = (row & 7) << 3;
      const float* sa = comb + abase + (size_t)row * (E_ * C_) + ct + k8;
      f32x4 a0 = *(const f32x4*)sa;
      f32x4 a1 = *(const f32x4*)(sa + 4);
      rs[cc] += a0[0] + a0[1] + a0[2] + a0[3] + a1[0] + a1[1] + a1[2] + a1[3];
      u32x4 pw = {cvtpk(a0[0], a0[1]), cvtpk(a0[2], a0[3]),
                  cvtpk(a1[0], a1[1]), cvtpk(a1[2], a1[3])};
      *(u32x4*)&lA[row * 64 + (k8 ^ sw)] = pw;
    }
#pragma unroll
    for (int cc = 0; cc < 4; cc++) {           // B: 256 rows x 64 c
      const int q = tid + 512 * cc;
      const int row = q >> 3;                  // 0..255
      const int k8 = (q & 7) << 3;
      const int sw = (row & 7) << 3;
      s16x8 pb = *(const s16x8*)(Bsrc + (size_t)row * C_ + ct + k8);
      *(s16x8*)&lB[row * 64 + (k8 ^ sw)] = pb;
    }
    __syncthreads();
#pragma unroll
    for (int kk = 0; kk < 2; kk++) {
      const int kb = kk * 32 + g * 8;
      s16x8 af[4], bf[4];
#pragma unroll
      for (int mi = 0; mi < 4; mi++) {
        const int r = wm * 64 + mi * 16 + lr;
        af[mi] = *(const s16x8*)&lA[r * 64 + (kb ^ ((r & 7) << 3))];
      }
#pragma unroll
      for (int ni = 0; ni < 4; ni++) {
        const int r = wn * 64 + ni * 16 + lr;
        bf[ni] = *(const s16x8*)&lB[r * 64 + (kb ^ ((r & 7) << 3))];
      }
#pragma unroll
      for (int mi = 0; mi < 4; mi++)
#pragma unroll
        for (int ni = 0; ni < 4; ni++)
          acc[mi][ni] = __builtin_amdgcn_mfma_f32_16x16x32_bf16(af[mi], bf[ni], acc[mi][ni], 0, 0, 0);
    }
  }
#pragma unroll
  for (int cc = 0; cc < 2; cc++) {
    float v = rs[cc];
    v += __shfl_xor(v, 1);
    v += __shfl_xor(v, 2);
    v += __shfl_xor(v, 4);
    if ((tid & 7) == 0)
      Se[((size_t)b * E_ + e) * T_ + mt * 128 + (tid >> 3) + 64 * cc] = v;
  }
#pragma unroll
  for (int mi = 0; mi < 4; mi++)
#pragma unroll
    for (int ni = 0; ni < 4; ni++)
#pragma unroll
      for (int r = 0; r < 4; r++) {
        const int tg = mt * 128 + wm * 64 + mi * 16 + g * 4 + r;
        const int ig = wn * 64 + ni * 16 + lr;            // 0..255 (full I)
        const int d = e * I_ + ig;
        const int dsw = (d & ~63) | (d & 7) | ((((d >> 3) & 7) ^ (tg & 7)) << 3);
        z[((size_t)b * T_ + tg) * D_ + dsw] = f2bf(acc[mi][ni][r]);
      }
}

// ---------------------------------------------------------------------------
// Kernel 4: out = z*wT^T + bias*S. 256x256, BK=64, 8 waves, SINGLE-buffered
// 64 KiB LDS -> 2 blocks/CU. Plain 2-barrier loop (m97 structure): the
// co-resident block provides MFMA/stage overlap (m114), same mechanism that
// puts gemm1/zgemm on the ~12 TB/s logical-byte wall. Cooperative-S epilogue.
// ---------------------------------------------------------------------------
__global__ __launch_bounds__(512, 2) void k_outgemm(const short* __restrict__ z,
                                                    const short* __restrict__ wT,
                                                    const float* __restrict__ bias,
                                                    const float* __restrict__ Se,
                                                    float* __restrict__ out) {
  __shared__ short lA[256 * 64];   // 32 KB
  __shared__ short lB[256 * 64];   // 32 KB
  const int tid = threadIdx.x;
  const int lane = tid & 63, wid = tid >> 6;
  const int wm = wid >> 2, wn = wid & 3;
  const int g = lane >> 4, lr = lane & 15;

  const int bid = blockIdx.x;
  const int swz = (bid & 7) * 64 + (bid >> 3);
  const int mt = swz >> 3, nt = swz & 7;
  const int row0 = mt * 256;
  const int col0 = nt * 256;

  const int srow = (wid << 4) + (lane >> 3);
  const int scol = (lane & 7) << 3;
  const short* Abase = z + (size_t)(row0 + srow) * D_ + scol;
  const short* Bbase = wT + (size_t)(col0 + srow) * D_ + scol;

  const f32x4 zero4 = {0.f, 0.f, 0.f, 0.f};
  f32x4 acc[8][4];
#pragma unroll
  for (int i = 0; i < 8; i++)
#pragma unroll
    for (int j = 0; j < 4; j++) acc[i][j] = zero4;

  s16x8 af[8], bf0[4], bf1[4];
  const int swr = (lr & 7) << 3;

  auto stage = [&](int dt) {   // all 4 half-tiles of K-tile dt
#pragma unroll
    for (int h = 0; h < 2; h++) {
      gll16(Abase + (size_t)(h * 128) * D_ + dt, &lA[(h * 128 + wid * 16) * 64]);
      gll16(Abase + (size_t)(h * 128 + 8) * D_ + dt, &lA[(h * 128 + wid * 16 + 8) * 64]);
      gll16(Bbase + (size_t)(h * 128) * D_ + dt, &lB[(h * 128 + wid * 16) * 64]);
      gll16(Bbase + (size_t)(h * 128 + 8) * D_ + dt, &lB[(h * 128 + wid * 16 + 8) * 64]);
    }
  };
  auto readA = [&](int mh) {
#pragma unroll
    for (int mi = 0; mi < 4; mi++) {
      const int r = mh * 128 + wm * 64 + mi * 16 + lr;
#pragma unroll
      for (int ks = 0; ks < 2; ks++)
        af[mi * 2 + ks] = *(const s16x8*)&lA[r * 64 + ((ks * 32 + g * 8) ^ swr)];
    }
  };
  auto readB = [&](int nh, s16x8* arr) {
#pragma unroll
    for (int ni = 0; ni < 2; ni++) {
      const int r = nh * 128 + wn * 32 + ni * 16 + lr;
#pragma unroll
      for (int ks = 0; ks < 2; ks++)
        arr[ni * 2 + ks] = *(const s16x8*)&lB[r * 64 + ((ks * 32 + g * 8) ^ swr)];
    }
  };
  auto mmaq = [&](int mh, int nh, const s16x8* bb) {
    __builtin_amdgcn_s_setprio(1);
#pragma unroll
    for (int mi = 0; mi < 4; mi++)
#pragma unroll
      for (int ni = 0; ni < 2; ni++)
#pragma unroll
        for (int ks = 0; ks < 2; ks++)
          acc[mh * 4 + mi][nh * 2 + ni] = __builtin_amdgcn_mfma_f32_16x16x32_bf16(
              af[mi * 2 + ks], bb[ni * 2 + ks], acc[mh * 4 + mi][nh * 2 + ni], 0, 0, 0);
    __builtin_amdgcn_s_setprio(0);
  };

  for (int t = 0; t < 32; ++t) {
    __syncthreads();            // LDS free (prev compute done)
    stage(t * 64);              // 8 gll/wave
    __syncthreads();            // LDS ready (compiler drains vmcnt before bar)
    readA(0); readB(0, bf0);
    mmaq(0, 0, bf0);
    readB(1, bf1);
    mmaq(0, 1, bf1);
    readA(1);
    mmaq(1, 0, bf0);
    mmaq(1, 1, bf1);
  }

  // cooperative S = sum_e Se for this block's 256 rows (LDS reuse of lA)
  __syncthreads();
  float* sS = (float*)lA;
  if (tid < 256) {
    const int bb = row0 >> 12, tt = (row0 & (T_ - 1)) + tid;
    float s = 0.f;
#pragma unroll
    for (int e = 0; e < E_; e++)
      s += Se[((size_t)(bb * E_ + e) << 12) + tt];
    sS[tid] = s;
  }
  __syncthreads();

  float bia[4];
#pragma unroll
  for (int nh = 0; nh < 2; nh++)
#pragma unroll
    for (int ni = 0; ni < 2; ni++)
      bia[nh * 2 + ni] = bias[col0 + nh * 128 + wn * 32 + ni * 16 + lr];
#pragma unroll
  for (int mh = 0; mh < 2; mh++)
#pragma unroll
    for (int mi = 0; mi < 4; mi++)
#pragma unroll
      for (int r = 0; r < 4; r++) {
        const int tg = row0 + mh * 128 + wm * 64 + mi * 16 + g * 4 + r;
        const float s = sS[tg - row0];
#pragma unroll
        for (int nh = 0; nh < 2; nh++)
#pragma unroll
          for (int ni = 0; ni < 2; ni++) {
            const int og = col0 + nh * 128 + wn * 32 + ni * 16 + lr;
            out[(size_t)tg * O_ + og] = acc[mh * 4 + mi][nh * 2 + ni][r] + bia[nh * 2 + ni] * s;
          }
      }
}

// ---------------------------------------------------------------------------
extern "C" void kernel_launch(void* const* d_in, const int* in_sizes, int n_in,
                              void* d_out, int out_size, void* d_ws, size_t ws_size,
                              hipStream_t stream) {
  const float* x    = (const float*)d_in[0];
  const float* comb = (const float*)d_in[1];
  const float* disp = (const float*)d_in[2];
  const float* w    = (const float*)d_in[3];
  const float* bias = (const float*)d_in[4];
  float* out = (float*)d_out;

  char* ws = (char*)d_ws;
  short* wT  = (short*)(ws);                    //  8,388,608 B  [O][D] bf16 (pre-swizzled)
  short* xdT = (short*)(ws + 8388608);          //  8,388,608 B  [B,E][I][C] bf16
  short* z   = (short*)(ws + 16777216);         // 67,108,864 B  [B][T][D] bf16 (pre-swizzled)
  float* xdP = (float*)(ws + 16777216);         // 33,554,432 B  2x split-K partials (aliases z; dead before zgemm)
  float* Se  = (float*)(ws + 83886080);         //    524,288 B  [B][E][T] f32

  k_gemm1<<<dim3(1280), dim3(512), 0, stream>>>(x, disp, w, wT, xdP);
  k_cvt<<<dim3(4096), dim3(256), 0, stream>>>(xdP, xdT);
  k_zgemm<<<dim3(1024), dim3(512), 0, stream>>>(comb, xdT, z, Se);
  k_outgemm<<<dim3(512), dim3(512), 0, stream>>>(z, wT, bias, Se, out);
}

// Round 17
// 326.383 us; speedup vs baseline: 1.1284x; 1.1284x over previous
//
#include <hip/hip_runtime.h>

typedef float f32x4 __attribute__((ext_vector_type(4)));
typedef short s16x8 __attribute__((ext_vector_type(8)));
typedef short s16x4 __attribute__((ext_vector_type(4)));
typedef unsigned u32x4 __attribute__((ext_vector_type(4)));
typedef unsigned u32x2 __attribute__((ext_vector_type(2)));

#define DEVI __device__ __forceinline__

static constexpr int B_ = 4, T_ = 4096, D_ = 2048, E_ = 8, C_ = 512, O_ = 2048, I_ = 256;
static constexpr size_t XDN = (size_t)B_ * E_ * I_ * C_;  // 4,194,304

DEVI short f2bf(float f) {
  unsigned u = __builtin_bit_cast(unsigned, f);
  u += 0x7FFFu + ((u >> 16) & 1u);
  return (short)(u >> 16);
}

// packed f32x2 -> bf16x2 (RNE), one VALU op
DEVI unsigned cvtpk(float lo, float hi) {
  unsigned r;
  asm("v_cvt_pk_bf16_f32 %0, %1, %2" : "=v"(r) : "v"(lo), "v"(hi));
  return r;
}

DEVI void gll16(const short* gsrc, short* ldst) {
  __builtin_amdgcn_global_load_lds(
      (const __attribute__((address_space(1))) void*)gsrc,
      (__attribute__((address_space(3))) void*)ldst, 16, 0, 0);
}

// ---------------------------------------------------------------------------
// Kernel 1 (FUSED): blocks [0,256) = gemm1 split-K=2; blocks [256,1280) =
// wT prep (w[e][o][i] f32 -> wT[o][e*256+i] bf16, pre-swizzled d8blk^(o&7)).
// gemm1: 128(i) x 256(c) tile, 512 thr / 8 waves (2Mx4N), acc[4][4].
// ---------------------------------------------------------------------------
__global__ __launch_bounds__(512, 2) void k_gemm1(const float* __restrict__ x,
                                                  const float* __restrict__ disp,
                                                  const float* __restrict__ w,
                                                  short* __restrict__ wT,
                                                  float* __restrict__ xdP) {
  __shared__ short lXT[128 * 64];  // [i][t] swizzled (16 KB)
  __shared__ short lDT[256 * 64];  // [c][t] swizzled (32 KB)
  const int tid = threadIdx.x;
  const int bid = blockIdx.x;

  if (bid >= 256) {  // ---- prep_wT role ----
    const int pb = bid - 256;
#pragma unroll
    for (int u = 0; u < 2; u++) {
      const int idx = (pb * 512 + tid) * 2 + u;   // [0, 1M)
      const int o = idx >> 9;
      const int dd = (idx & 511) << 2;            // d = e*256+i
      const int e = dd >> 8, i = dd & 255;
      f32x4 v = *(const f32x4*)(w + (((size_t)e * O_ + o) * I_ + i));
      u32x2 p = {cvtpk(v[0], v[1]), cvtpk(v[2], v[3])};
      const int dsw = (dd & ~63) | (dd & 7) | ((((dd >> 3) & 7) ^ (o & 7)) << 3);
      *(u32x2*)(wT + (size_t)o * D_ + dsw) = p;
    }
    return;
  }

  // ---- gemm1 role ----
  const int xcd = bid & 7, slot = bid >> 3;      // slot 0..31
  const int grp = (slot >> 2) * 8 + xcd;         // 0..63 = 32 be x 2 kc
  const int jj = slot & 3;                       // tile within group
  const int be = grp >> 1, kc = grp & 1;
  const int mt = jj >> 1, nt = jj & 1;
  const int b = be >> 3, e = be & 7;
  const int lane = tid & 63, wid = tid >> 6;
  const int wm = wid >> 2, wn = wid & 3;         // 2 x 4 waves
  const int g = lane >> 4, lr = lane & 15;

  const size_t xbase = (size_t)b * T_ * D_ + (size_t)e * I_ + (size_t)mt * 128;
  const size_t dbase = (size_t)b * T_ * (E_ * C_) + (size_t)e * C_ + (size_t)nt * 256;

  const f32x4 z4 = {0.f, 0.f, 0.f, 0.f};
  f32x4 acc[4][4];
#pragma unroll
  for (int i = 0; i < 4; i++)
#pragma unroll
    for (int j = 0; j < 4; j++) acc[i][j] = z4;

  const int xt0 = (tid >> 4) * 2;    // 0..62  (x staging t-pair)
  const int xi8 = (tid & 15) * 8;    // 0..120 (x staging i-chunk)
  const int dt0 = (tid >> 5) * 2;    // 0..30  (disp staging t-pair, + tt*32)
  const int dc8 = (tid & 31) * 8;    // 0..248 (disp staging c-chunk)
  const int q7 = tid & 7;

  f32x4 xa0, xa1, xb0, xb1;
  f32x4 da[2][4];
  auto loadRegs = [&](int kt) {
    const float* sx = x + xbase + (size_t)(kt + xt0) * D_ + xi8;
    xa0 = *(const f32x4*)sx;
    xa1 = *(const f32x4*)(sx + 4);
    xb0 = *(const f32x4*)(sx + D_);
    xb1 = *(const f32x4*)(sx + D_ + 4);
#pragma unroll
    for (int tt = 0; tt < 2; tt++) {
      const float* sd = disp + dbase + (size_t)(kt + tt * 32 + dt0) * (E_ * C_) + dc8;
      da[tt][0] = *(const f32x4*)sd;
      da[tt][1] = *(const f32x4*)(sd + 4);
      da[tt][2] = *(const f32x4*)(sd + E_ * C_);
      da[tt][3] = *(const f32x4*)(sd + E_ * C_ + 4);
    }
  };
  auto writeLds = [&]() {
#pragma unroll
    for (int j = 0; j < 8; j++) {
      const int i = xi8 + j;
      const int ad = i * 64 + (xt0 ^ ((j ^ q7) << 3));
      float va = (j < 4) ? xa0[j] : xa1[j - 4];
      float vb = (j < 4) ? xb0[j] : xb1[j - 4];
      *(unsigned*)&lXT[ad] = cvtpk(va, vb);
    }
#pragma unroll
    for (int tt = 0; tt < 2; tt++)
#pragma unroll
      for (int j = 0; j < 8; j++) {
        const int c = dc8 + j;
        const int ad = c * 64 + ((tt * 32 + dt0) ^ ((j ^ q7) << 3));
        float ua = (j < 4) ? da[tt][0][j] : da[tt][1][j - 4];
        float ub = (j < 4) ? da[tt][2][j] : da[tt][3][j - 4];
        *(unsigned*)&lDT[ad] = cvtpk(ua, ub);
      }
  };

  const int k0 = kc * 2048, kend = k0 + 2048;
  loadRegs(k0);
  for (int kt = k0; kt < kend; kt += 64) {
    __syncthreads();
    writeLds();
    if (kt + 64 < kend) loadRegs(kt + 64);
    __syncthreads();
#pragma unroll
    for (int kk = 0; kk < 2; kk++) {
      const int tb = kk * 32 + g * 8;
      s16x8 af[4], bfr[4];
#pragma unroll
      for (int mi = 0; mi < 4; mi++) {
        const int r = wm * 64 + mi * 16 + lr;
        const int sws = (((r & 7) ^ ((r >> 3) & 7)) << 3);
        af[mi] = *(const s16x8*)&lXT[r * 64 + (tb ^ sws)];
      }
#pragma unroll
      for (int ni = 0; ni < 4; ni++) {
        const int r = wn * 64 + ni * 16 + lr;
        const int sws = (((r & 7) ^ ((r >> 3) & 7)) << 3);
        bfr[ni] = *(const s16x8*)&lDT[r * 64 + (tb ^ sws)];
      }
#pragma unroll
      for (int mi = 0; mi < 4; mi++)
#pragma unroll
        for (int ni = 0; ni < 4; ni++)
          acc[mi][ni] = __builtin_amdgcn_mfma_f32_16x16x32_bf16(af[mi], bfr[ni], acc[mi][ni], 0, 0, 0);
    }
  }

  float* op = xdP + (size_t)kc * XDN + (size_t)be * I_ * C_;
#pragma unroll
  for (int mi = 0; mi < 4; mi++)
#pragma unroll
    for (int ni = 0; ni < 4; ni++)
#pragma unroll
      for (int r = 0; r < 4; r++) {
        const int ig = mt * 128 + wm * 64 + mi * 16 + g * 4 + r;
        const int cg = nt * 256 + wn * 64 + ni * 16 + lr;
        op[(size_t)ig * C_ + cg] = acc[mi][ni][r];
      }
}

// ---------------------------------------------------------------------------
// Kernel 1b: xdT = bf16(P0 + P1)   (4M elements; split-K reducer)
// ---------------------------------------------------------------------------
__global__ __launch_bounds__(256) void k_cvt(const float* __restrict__ xdP,
                                             short* __restrict__ xdT) {
  size_t idx = (size_t)blockIdx.x * 256 + threadIdx.x;
  f32x4 a = *(const f32x4*)(xdP + idx * 4);
  f32x4 b = *(const f32x4*)(xdP + XDN + idx * 4);
#pragma unroll
  for (int j = 0; j < 4; j++) a[j] += b[j];
  u32x2 p = {cvtpk(a[0], a[1]), cvtpk(a[2], a[3])};
  *(u32x2*)(xdT + idx * 4) = p;
}

// ---------------------------------------------------------------------------
// Kernel 2: z[b][t][d'] = sum_c comb[b,t,e,c]*xdT[b,e][i][c] (bf16)
// 128(t) x 256(i full-I) tile; comb read once. Se by every block.
// z PRE-SWIZZLED (d8blk ^ (t&7)). Grid 1024 = 32 be x 32 mt.
// ---------------------------------------------------------------------------
__global__ __launch_bounds__(512, 2) void k_zgemm(const float* __restrict__ comb,
                                                  const short* __restrict__ xdT,
                                                  short* __restrict__ z,
                                                  float* __restrict__ Se) {
  __shared__ short lA[128 * 64];   // [t][c] swizzled (16 KB)
  __shared__ short lB[256 * 64];   // [i][c] swizzled (32 KB)
  const int tid = threadIdx.x;
  const int bid = blockIdx.x;
  const int be = bid >> 5, mt = bid & 31;
  const int b = be >> 3, e = be & 7;
  const int lane = tid & 63, wid = tid >> 6;
  const int wm = wid >> 2, wn = wid & 3;         // 2 x 4 waves
  const int g = lane >> 4, lr = lane & 15;

  const size_t abase = (size_t)b * T_ * (E_ * C_) + (size_t)(mt * 128) * (E_ * C_) + (size_t)e * C_;
  const short* Bsrc = xdT + (size_t)be * I_ * C_;

  float rs[2] = {0.f, 0.f};
  const f32x4 z4 = {0.f, 0.f, 0.f, 0.f};
  f32x4 acc[4][4];
#pragma unroll
  for (int i = 0; i < 4; i++)
#pragma unroll
    for (int j = 0; j < 4; j++) acc[i][j] = z4;

  for (int ct = 0; ct < C_; ct += 64) {
    __syncthreads();
#pragma unroll
    for (int cc = 0; cc < 2; cc++) {           // A: 128 rows x 64 c
      const int q = tid + 512 * cc;
      const int row = q >> 3;                  // 0..127
      const int k8 = (q & 7) << 3;
      const int sw = (row & 7) << 3;
      const float* sa = comb + abase + (size_t)row * (E_ * C_) + ct + k8;
      f32x4 a0 = *(const f32x4*)sa;
      f32x4 a1 = *(const f32x4*)(sa + 4);
      rs[cc] += a0[0] + a0[1] + a0[2] + a0[3] + a1[0] + a1[1] + a1[2] + a1[3];
      u32x4 pw = {cvtpk(a0[0], a0[1]), cvtpk(a0[2], a0[3]),
                  cvtpk(a1[0], a1[1]), cvtpk(a1[2], a1[3])};
      *(u32x4*)&lA[row * 64 + (k8 ^ sw)] = pw;
    }
#pragma unroll
    for (int cc = 0; cc < 4; cc++) {           // B: 256 rows x 64 c
      const int q = tid + 512 * cc;
      const int row = q >> 3;                  // 0..255
      const int k8 = (q & 7) << 3;
      const int sw = (row & 7) << 3;
      s16x8 pb = *(const s16x8*)(Bsrc + (size_t)row * C_ + ct + k8);
      *(s16x8*)&lB[row * 64 + (k8 ^ sw)] = pb;
    }
    __syncthreads();
#pragma unroll
    for (int kk = 0; kk < 2; kk++) {
      const int kb = kk * 32 + g * 8;
      s16x8 af[4], bf[4];
#pragma unroll
      for (int mi = 0; mi < 4; mi++) {
        const int r = wm * 64 + mi * 16 + lr;
        af[mi] = *(const s16x8*)&lA[r * 64 + (kb ^ ((r & 7) << 3))];
      }
#pragma unroll
      for (int ni = 0; ni < 4; ni++) {
        const int r = wn * 64 + ni * 16 + lr;
        bf[ni] = *(const s16x8*)&lB[r * 64 + (kb ^ ((r & 7) << 3))];
      }
#pragma unroll
      for (int mi = 0; mi < 4; mi++)
#pragma unroll
        for (int ni = 0; ni < 4; ni++)
          acc[mi][ni] = __builtin_amdgcn_mfma_f32_16x16x32_bf16(af[mi], bf[ni], acc[mi][ni], 0, 0, 0);
    }
  }
#pragma unroll
  for (int cc = 0; cc < 2; cc++) {
    float v = rs[cc];
    v += __shfl_xor(v, 1);
    v += __shfl_xor(v, 2);
    v += __shfl_xor(v, 4);
    if ((tid & 7) == 0)
      Se[((size_t)b * E_ + e) * T_ + mt * 128 + (tid >> 3) + 64 * cc] = v;
  }
#pragma unroll
  for (int mi = 0; mi < 4; mi++)
#pragma unroll
    for (int ni = 0; ni < 4; ni++)
#pragma unroll
      for (int r = 0; r < 4; r++) {
        const int tg = mt * 128 + wm * 64 + mi * 16 + g * 4 + r;
        const int ig = wn * 64 + ni * 16 + lr;            // 0..255 (full I)
        const int d = e * I_ + ig;
        const int dsw = (d & ~63) | (d & 7) | ((((d >> 3) & 7) ^ (tg & 7)) << 3);
        z[((size_t)b * T_ + tg) * D_ + dsw] = f2bf(acc[mi][ni][r]);
      }
}

// ---------------------------------------------------------------------------
// Kernel 4 (v3, zgemm-clone shape): out = z*wT^T + bias*S.
// 128(rows) x 256(o-cols) tile, 8 waves (2Mx4N), per-wave 64x64 (acc[4][4] =
// 64 AGPR; total <=128 regs enforced by launch_bounds(512,4)) -> 2 blocks/CU
// (the register cap, not LDS, was pinning occupancy at 1 block). Single
// 48 KiB LDS, 2-barrier loop — proven regime of gemm1/zgemm at the
// ~12 TB/s logical-byte wall. gll16 staging of pre-swizzled z/wT (local row
// == global row mod 8). Grid 1024, XCD-chunked. Cooperative-S epilogue.
// ---------------------------------------------------------------------------
__global__ __launch_bounds__(512, 4) void k_outgemm(const short* __restrict__ z,
                                                    const short* __restrict__ wT,
                                                    const float* __restrict__ bias,
                                                    const float* __restrict__ Se,
                                                    float* __restrict__ out) {
  __shared__ short lA[128 * 64];   // z rows     (16 KB)
  __shared__ short lB[256 * 64];   // wT o-rows  (32 KB)
  const int tid = threadIdx.x;
  const int lane = tid & 63, wid = tid >> 6;
  const int wm = wid >> 2, wn = wid & 3;         // 2 x 4 waves
  const int g = lane >> 4, lr = lane & 15;

  const int bid = blockIdx.x;
  const int swz = (bid & 7) * 128 + (bid >> 3);  // XCD chunk of 128
  const int mt = swz >> 3, nt = swz & 7;         // 128 mt x 8 nt
  const int row0 = mt * 128;                     // token rows (B*T flat)
  const int col0 = nt * 256;                     // O cols

  const int srow = lane >> 3;                    // 0..7 within 8-row group
  const int scol = (lane & 7) << 3;              // shorts
  const short* Abase = z + (size_t)(row0 + wid * 16 + srow) * D_ + scol;
  const short* Bbase = wT + (size_t)(col0 + wid * 32 + srow) * D_ + scol;

  const f32x4 zero4 = {0.f, 0.f, 0.f, 0.f};
  f32x4 acc[4][4];
#pragma unroll
  for (int i = 0; i < 4; i++)
#pragma unroll
    for (int j = 0; j < 4; j++) acc[i][j] = zero4;

  for (int t = 0; t < 32; ++t) {
    const int dt = t * 64;
    __syncthreads();
    // stage A: 128 rows (wave covers 16: 2 gll), B: 256 rows (wave covers 32: 4 gll)
    gll16(Abase + dt, &lA[(wid * 16 + srow) * 64]);
    gll16(Abase + (size_t)8 * D_ + dt, &lA[(wid * 16 + 8 + srow) * 64]);
#pragma unroll
    for (int h = 0; h < 4; h++)
      gll16(Bbase + (size_t)(h * 8) * D_ + dt, &lB[(wid * 32 + h * 8 + srow) * 64]);
    __syncthreads();
#pragma unroll
    for (int kk = 0; kk < 2; kk++) {
      const int kb = kk * 32 + g * 8;
      s16x8 af[4], bf[4];
#pragma unroll
      for (int mi = 0; mi < 4; mi++) {
        const int r = wm * 64 + mi * 16 + lr;
        af[mi] = *(const s16x8*)&lA[r * 64 + (kb ^ ((r & 7) << 3))];
      }
#pragma unroll
      for (int ni = 0; ni < 4; ni++) {
        const int r = wn * 64 + ni * 16 + lr;
        bf[ni] = *(const s16x8*)&lB[r * 64 + (kb ^ ((r & 7) << 3))];
      }
#pragma unroll
      for (int mi = 0; mi < 4; mi++)
#pragma unroll
        for (int ni = 0; ni < 4; ni++)
          acc[mi][ni] = __builtin_amdgcn_mfma_f32_16x16x32_bf16(af[mi], bf[ni], acc[mi][ni], 0, 0, 0);
    }
  }

  // cooperative S = sum_e Se for this block's 128 rows (LDS reuse of lA)
  __syncthreads();
  float* sS = (float*)lA;
  if (tid < 128) {
    const int bb = row0 >> 12, tt = (row0 & (T_ - 1)) + tid;
    float s = 0.f;
#pragma unroll
    for (int e = 0; e < E_; e++)
      s += Se[((size_t)(bb * E_ + e) << 12) + tt];
    sS[tid] = s;
  }
  __syncthreads();

  float bia[4];
#pragma unroll
  for (int ni = 0; ni < 4; ni++) bia[ni] = bias[col0 + wn * 64 + ni * 16 + lr];
#pragma unroll
  for (int mi = 0; mi < 4; mi++)
#pragma unroll
    for (int r = 0; r < 4; r++) {
      const int rl = wm * 64 + mi * 16 + g * 4 + r;     // local row
      const int tg = row0 + rl;
      const float s = sS[rl];
#pragma unroll
      for (int ni = 0; ni < 4; ni++) {
        const int og = col0 + wn * 64 + ni * 16 + lr;
        out[(size_t)tg * O_ + og] = acc[mi][ni][r] + bia[ni] * s;
      }
    }
}

// ---------------------------------------------------------------------------
extern "C" void kernel_launch(void* const* d_in, const int* in_sizes, int n_in,
                              void* d_out, int out_size, void* d_ws, size_t ws_size,
                              hipStream_t stream) {
  const float* x    = (const float*)d_in[0];
  const float* comb = (const float*)d_in[1];
  const float* disp = (const float*)d_in[2];
  const float* w    = (const float*)d_in[3];
  const float* bias = (const float*)d_in[4];
  float* out = (float*)d_out;

  char* ws = (char*)d_ws;
  short* wT  = (short*)(ws);                    //  8,388,608 B  [O][D] bf16 (pre-swizzled)
  short* xdT = (short*)(ws + 8388608);          //  8,388,608 B  [B,E][I][C] bf16
  short* z   = (short*)(ws + 16777216);         // 67,108,864 B  [B][T][D] bf16 (pre-swizzled)
  float* xdP = (float*)(ws + 16777216);         // 33,554,432 B  2x split-K partials (aliases z; dead before zgemm)
  float* Se  = (float*)(ws + 83886080);         //    524,288 B  [B][E][T] f32

  k_gemm1<<<dim3(1280), dim3(512), 0, stream>>>(x, disp, w, wT, xdP);
  k_cvt<<<dim3(4096), dim3(256), 0, stream>>>(xdP, xdT);
  k_zgemm<<<dim3(1024), dim3(512), 0, stream>>>(comb, xdT, z, Se);
  k_outgemm<<<dim3(1024), dim3(512), 0, stream>>>(z, wT, bias, Se, out);
}

// Round 18
// 320.951 us; speedup vs baseline: 1.1475x; 1.0169x over previous
//
#include <hip/hip_runtime.h>

typedef float f32x4 __attribute__((ext_vector_type(4)));
typedef short s16x8 __attribute__((ext_vector_type(8)));
typedef short s16x4 __attribute__((ext_vector_type(4)));
typedef unsigned u32x4 __attribute__((ext_vector_type(4)));
typedef unsigned u32x2 __attribute__((ext_vector_type(2)));

#define DEVI __device__ __forceinline__

static constexpr int B_ = 4, T_ = 4096, D_ = 2048, E_ = 8, C_ = 512, O_ = 2048, I_ = 256;
static constexpr size_t XDN = (size_t)B_ * E_ * I_ * C_;  // 4,194,304

DEVI short f2bf(float f) {
  unsigned u = __builtin_bit_cast(unsigned, f);
  u += 0x7FFFu + ((u >> 16) & 1u);
  return (short)(u >> 16);
}

// packed f32x2 -> bf16x2 (RNE), one VALU op
DEVI unsigned cvtpk(float lo, float hi) {
  unsigned r;
  asm("v_cvt_pk_bf16_f32 %0, %1, %2" : "=v"(r) : "v"(lo), "v"(hi));
  return r;
}

DEVI void gll16(const short* gsrc, short* ldst) {
  __builtin_amdgcn_global_load_lds(
      (const __attribute__((address_space(1))) void*)gsrc,
      (__attribute__((address_space(3))) void*)ldst, 16, 0, 0);
}

// ---------------------------------------------------------------------------
// Kernel 1 (FUSED): blocks [0,256) = gemm1 split-K=2; blocks [256,1280) =
// wT prep (w[e][o][i] f32 -> wT[o][e*256+i] bf16, pre-swizzled d8blk^(o&7)).
// gemm1: 128(i) x 256(c) tile, 512 thr / 8 waves (2Mx4N), acc[4][4].
// ---------------------------------------------------------------------------
__global__ __launch_bounds__(512, 2) void k_gemm1(const float* __restrict__ x,
                                                  const float* __restrict__ disp,
                                                  const float* __restrict__ w,
                                                  short* __restrict__ wT,
                                                  float* __restrict__ xdP) {
  __shared__ short lXT[128 * 64];  // [i][t] swizzled (16 KB)
  __shared__ short lDT[256 * 64];  // [c][t] swizzled (32 KB)
  const int tid = threadIdx.x;
  const int bid = blockIdx.x;

  if (bid >= 256) {  // ---- prep_wT role ----
    const int pb = bid - 256;
#pragma unroll
    for (int u = 0; u < 2; u++) {
      const int idx = (pb * 512 + tid) * 2 + u;   // [0, 1M)
      const int o = idx >> 9;
      const int dd = (idx & 511) << 2;            // d = e*256+i
      const int e = dd >> 8, i = dd & 255;
      f32x4 v = *(const f32x4*)(w + (((size_t)e * O_ + o) * I_ + i));
      u32x2 p = {cvtpk(v[0], v[1]), cvtpk(v[2], v[3])};
      const int dsw = (dd & ~63) | (dd & 7) | ((((dd >> 3) & 7) ^ (o & 7)) << 3);
      *(u32x2*)(wT + (size_t)o * D_ + dsw) = p;
    }
    return;
  }

  // ---- gemm1 role ----
  const int xcd = bid & 7, slot = bid >> 3;      // slot 0..31
  const int grp = (slot >> 2) * 8 + xcd;         // 0..63 = 32 be x 2 kc
  const int jj = slot & 3;                       // tile within group
  const int be = grp >> 1, kc = grp & 1;
  const int mt = jj >> 1, nt = jj & 1;
  const int b = be >> 3, e = be & 7;
  const int lane = tid & 63, wid = tid >> 6;
  const int wm = wid >> 2, wn = wid & 3;         // 2 x 4 waves
  const int g = lane >> 4, lr = lane & 15;

  const size_t xbase = (size_t)b * T_ * D_ + (size_t)e * I_ + (size_t)mt * 128;
  const size_t dbase = (size_t)b * T_ * (E_ * C_) + (size_t)e * C_ + (size_t)nt * 256;

  const f32x4 z4 = {0.f, 0.f, 0.f, 0.f};
  f32x4 acc[4][4];
#pragma unroll
  for (int i = 0; i < 4; i++)
#pragma unroll
    for (int j = 0; j < 4; j++) acc[i][j] = z4;

  const int xt0 = (tid >> 4) * 2;    // 0..62  (x staging t-pair)
  const int xi8 = (tid & 15) * 8;    // 0..120 (x staging i-chunk)
  const int dt0 = (tid >> 5) * 2;    // 0..30  (disp staging t-pair, + tt*32)
  const int dc8 = (tid & 31) * 8;    // 0..248 (disp staging c-chunk)
  const int q7 = tid & 7;

  f32x4 xa0, xa1, xb0, xb1;
  f32x4 da[2][4];
  auto loadRegs = [&](int kt) {
    const float* sx = x + xbase + (size_t)(kt + xt0) * D_ + xi8;
    xa0 = *(const f32x4*)sx;
    xa1 = *(const f32x4*)(sx + 4);
    xb0 = *(const f32x4*)(sx + D_);
    xb1 = *(const f32x4*)(sx + D_ + 4);
#pragma unroll
    for (int tt = 0; tt < 2; tt++) {
      const float* sd = disp + dbase + (size_t)(kt + tt * 32 + dt0) * (E_ * C_) + dc8;
      da[tt][0] = *(const f32x4*)sd;
      da[tt][1] = *(const f32x4*)(sd + 4);
      da[tt][2] = *(const f32x4*)(sd + E_ * C_);
      da[tt][3] = *(const f32x4*)(sd + E_ * C_ + 4);
    }
  };
  auto writeLds = [&]() {
#pragma unroll
    for (int j = 0; j < 8; j++) {
      const int i = xi8 + j;
      const int ad = i * 64 + (xt0 ^ ((j ^ q7) << 3));
      float va = (j < 4) ? xa0[j] : xa1[j - 4];
      float vb = (j < 4) ? xb0[j] : xb1[j - 4];
      *(unsigned*)&lXT[ad] = cvtpk(va, vb);
    }
#pragma unroll
    for (int tt = 0; tt < 2; tt++)
#pragma unroll
      for (int j = 0; j < 8; j++) {
        const int c = dc8 + j;
        const int ad = c * 64 + ((tt * 32 + dt0) ^ ((j ^ q7) << 3));
        float ua = (j < 4) ? da[tt][0][j] : da[tt][1][j - 4];
        float ub = (j < 4) ? da[tt][2][j] : da[tt][3][j - 4];
        *(unsigned*)&lDT[ad] = cvtpk(ua, ub);
      }
  };

  const int k0 = kc * 2048, kend = k0 + 2048;
  loadRegs(k0);
  for (int kt = k0; kt < kend; kt += 64) {
    __syncthreads();
    writeLds();
    if (kt + 64 < kend) loadRegs(kt + 64);
    __syncthreads();
#pragma unroll
    for (int kk = 0; kk < 2; kk++) {
      const int tb = kk * 32 + g * 8;
      s16x8 af[4], bfr[4];
#pragma unroll
      for (int mi = 0; mi < 4; mi++) {
        const int r = wm * 64 + mi * 16 + lr;
        const int sws = (((r & 7) ^ ((r >> 3) & 7)) << 3);
        af[mi] = *(const s16x8*)&lXT[r * 64 + (tb ^ sws)];
      }
#pragma unroll
      for (int ni = 0; ni < 4; ni++) {
        const int r = wn * 64 + ni * 16 + lr;
        const int sws = (((r & 7) ^ ((r >> 3) & 7)) << 3);
        bfr[ni] = *(const s16x8*)&lDT[r * 64 + (tb ^ sws)];
      }
#pragma unroll
      for (int mi = 0; mi < 4; mi++)
#pragma unroll
        for (int ni = 0; ni < 4; ni++)
          acc[mi][ni] = __builtin_amdgcn_mfma_f32_16x16x32_bf16(af[mi], bfr[ni], acc[mi][ni], 0, 0, 0);
    }
  }

  float* op = xdP + (size_t)kc * XDN + (size_t)be * I_ * C_;
#pragma unroll
  for (int mi = 0; mi < 4; mi++)
#pragma unroll
    for (int ni = 0; ni < 4; ni++)
#pragma unroll
      for (int r = 0; r < 4; r++) {
        const int ig = mt * 128 + wm * 64 + mi * 16 + g * 4 + r;
        const int cg = nt * 256 + wn * 64 + ni * 16 + lr;
        op[(size_t)ig * C_ + cg] = acc[mi][ni][r];
      }
}

// ---------------------------------------------------------------------------
// Kernel 1b: xdT = bf16(P0 + P1)   (4M elements; split-K reducer)
// ---------------------------------------------------------------------------
__global__ __launch_bounds__(256) void k_cvt(const float* __restrict__ xdP,
                                             short* __restrict__ xdT) {
  size_t idx = (size_t)blockIdx.x * 256 + threadIdx.x;
  f32x4 a = *(const f32x4*)(xdP + idx * 4);
  f32x4 b = *(const f32x4*)(xdP + XDN + idx * 4);
#pragma unroll
  for (int j = 0; j < 4; j++) a[j] += b[j];
  u32x2 p = {cvtpk(a[0], a[1]), cvtpk(a[2], a[3])};
  *(u32x2*)(xdT + idx * 4) = p;
}

// ---------------------------------------------------------------------------
// Kernel 2: z[b][t][d'] = sum_c comb[b,t,e,c]*xdT[b,e][i][c] (bf16)
// 128(t) x 256(i full-I) tile; comb read once. Se by every block.
// z PRE-SWIZZLED (d8blk ^ (t&7)). Grid 1024 = 32 be x 32 mt.
// ---------------------------------------------------------------------------
__global__ __launch_bounds__(512, 2) void k_zgemm(const float* __restrict__ comb,
                                                  const short* __restrict__ xdT,
                                                  short* __restrict__ z,
                                                  float* __restrict__ Se) {
  __shared__ short lA[128 * 64];   // [t][c] swizzled (16 KB)
  __shared__ short lB[256 * 64];   // [i][c] swizzled (32 KB)
  const int tid = threadIdx.x;
  const int bid = blockIdx.x;
  const int be = bid >> 5, mt = bid & 31;
  const int b = be >> 3, e = be & 7;
  const int lane = tid & 63, wid = tid >> 6;
  const int wm = wid >> 2, wn = wid & 3;         // 2 x 4 waves
  const int g = lane >> 4, lr = lane & 15;

  const size_t abase = (size_t)b * T_ * (E_ * C_) + (size_t)(mt * 128) * (E_ * C_) + (size_t)e * C_;
  const short* Bsrc = xdT + (size_t)be * I_ * C_;

  float rs[2] = {0.f, 0.f};
  const f32x4 z4 = {0.f, 0.f, 0.f, 0.f};
  f32x4 acc[4][4];
#pragma unroll
  for (int i = 0; i < 4; i++)
#pragma unroll
    for (int j = 0; j < 4; j++) acc[i][j] = z4;

  for (int ct = 0; ct < C_; ct += 64) {
    __syncthreads();
#pragma unroll
    for (int cc = 0; cc < 2; cc++) {           // A: 128 rows x 64 c
      const int q = tid + 512 * cc;
      const int row = q >> 3;                  // 0..127
      const int k8 = (q & 7) << 3;
      const int sw = (row & 7) << 3;
      const float* sa = comb + abase + (size_t)row * (E_ * C_) + ct + k8;
      f32x4 a0 = *(const f32x4*)sa;
      f32x4 a1 = *(const f32x4*)(sa + 4);
      rs[cc] += a0[0] + a0[1] + a0[2] + a0[3] + a1[0] + a1[1] + a1[2] + a1[3];
      u32x4 pw = {cvtpk(a0[0], a0[1]), cvtpk(a0[2], a0[3]),
                  cvtpk(a1[0], a1[1]), cvtpk(a1[2], a1[3])};
      *(u32x4*)&lA[row * 64 + (k8 ^ sw)] = pw;
    }
#pragma unroll
    for (int cc = 0; cc < 4; cc++) {           // B: 256 rows x 64 c
      const int q = tid + 512 * cc;
      const int row = q >> 3;                  // 0..255
      const int k8 = (q & 7) << 3;
      const int sw = (row & 7) << 3;
      s16x8 pb = *(const s16x8*)(Bsrc + (size_t)row * C_ + ct + k8);
      *(s16x8*)&lB[row * 64 + (k8 ^ sw)] = pb;
    }
    __syncthreads();
#pragma unroll
    for (int kk = 0; kk < 2; kk++) {
      const int kb = kk * 32 + g * 8;
      s16x8 af[4], bf[4];
#pragma unroll
      for (int mi = 0; mi < 4; mi++) {
        const int r = wm * 64 + mi * 16 + lr;
        af[mi] = *(const s16x8*)&lA[r * 64 + (kb ^ ((r & 7) << 3))];
      }
#pragma unroll
      for (int ni = 0; ni < 4; ni++) {
        const int r = wn * 64 + ni * 16 + lr;
        bf[ni] = *(const s16x8*)&lB[r * 64 + (kb ^ ((r & 7) << 3))];
      }
#pragma unroll
      for (int mi = 0; mi < 4; mi++)
#pragma unroll
        for (int ni = 0; ni < 4; ni++)
          acc[mi][ni] = __builtin_amdgcn_mfma_f32_16x16x32_bf16(af[mi], bf[ni], acc[mi][ni], 0, 0, 0);
    }
  }
#pragma unroll
  for (int cc = 0; cc < 2; cc++) {
    float v = rs[cc];
    v += __shfl_xor(v, 1);
    v += __shfl_xor(v, 2);
    v += __shfl_xor(v, 4);
    if ((tid & 7) == 0)
      Se[((size_t)b * E_ + e) * T_ + mt * 128 + (tid >> 3) + 64 * cc] = v;
  }
#pragma unroll
  for (int mi = 0; mi < 4; mi++)
#pragma unroll
    for (int ni = 0; ni < 4; ni++)
#pragma unroll
      for (int r = 0; r < 4; r++) {
        const int tg = mt * 128 + wm * 64 + mi * 16 + g * 4 + r;
        const int ig = wn * 64 + ni * 16 + lr;            // 0..255 (full I)
        const int d = e * I_ + ig;
        const int dsw = (d & ~63) | (d & 7) | ((((d >> 3) & 7) ^ (tg & 7)) << 3);
        z[((size_t)b * T_ + tg) * D_ + dsw] = f2bf(acc[mi][ni][r]);
      }
}

// ---------------------------------------------------------------------------
// Kernel 4 (v3 + L2-aware XCD map): out = z*wT^T + bias*S.
// 128(rows) x 256(o-cols), 8 waves, acc[4][4], 48 KiB LDS, 2 blocks/CU.
// XCD x owns (mt-half, nt-pair): wT working set/XCD = 2 MB -> L2-resident
// (was 8 MB, thrashing: outgemm's staging ran 8.8 TB/s vs zgemm's 12.8).
// Consecutive blocks in an XCD share the z row-panel (read 2x back-to-back).
// ---------------------------------------------------------------------------
__global__ __launch_bounds__(512, 4) void k_outgemm(const short* __restrict__ z,
                                                    const short* __restrict__ wT,
                                                    const float* __restrict__ bias,
                                                    const float* __restrict__ Se,
                                                    float* __restrict__ out) {
  __shared__ short lA[128 * 64];   // z rows     (16 KB)
  __shared__ short lB[256 * 64];   // wT o-rows  (32 KB)
  const int tid = threadIdx.x;
  const int lane = tid & 63, wid = tid >> 6;
  const int wm = wid >> 2, wn = wid & 3;         // 2 x 4 waves
  const int g = lane >> 4, lr = lane & 15;

  const int bid = blockIdx.x;
  const int xg = bid & 7;                        // XCD
  const int mh = xg >> 2, np = xg & 3;           // mt-half, nt-pair
  const int idx = bid >> 3;                      // 0..127 = 64 mt x 2 nt
  const int mt = mh * 64 + (idx >> 1);
  const int nt = np * 2 + (idx & 1);
  const int row0 = mt * 128;                     // token rows (B*T flat)
  const int col0 = nt * 256;                     // O cols

  const int srow = lane >> 3;                    // 0..7 within 8-row group
  const int scol = (lane & 7) << 3;              // shorts
  const short* Abase = z + (size_t)(row0 + wid * 16 + srow) * D_ + scol;
  const short* Bbase = wT + (size_t)(col0 + wid * 32 + srow) * D_ + scol;

  const f32x4 zero4 = {0.f, 0.f, 0.f, 0.f};
  f32x4 acc[4][4];
#pragma unroll
  for (int i = 0; i < 4; i++)
#pragma unroll
    for (int j = 0; j < 4; j++) acc[i][j] = zero4;

  for (int t = 0; t < 32; ++t) {
    const int dt = t * 64;
    __syncthreads();
    // stage A: 128 rows (wave covers 16: 2 gll), B: 256 rows (wave covers 32: 4 gll)
    gll16(Abase + dt, &lA[(wid * 16 + srow) * 64]);
    gll16(Abase + (size_t)8 * D_ + dt, &lA[(wid * 16 + 8 + srow) * 64]);
#pragma unroll
    for (int h = 0; h < 4; h++)
      gll16(Bbase + (size_t)(h * 8) * D_ + dt, &lB[(wid * 32 + h * 8 + srow) * 64]);
    __syncthreads();
#pragma unroll
    for (int kk = 0; kk < 2; kk++) {
      const int kb = kk * 32 + g * 8;
      s16x8 af[4], bf[4];
#pragma unroll
      for (int mi = 0; mi < 4; mi++) {
        const int r = wm * 64 + mi * 16 + lr;
        af[mi] = *(const s16x8*)&lA[r * 64 + (kb ^ ((r & 7) << 3))];
      }
#pragma unroll
      for (int ni = 0; ni < 4; ni++) {
        const int r = wn * 64 + ni * 16 + lr;
        bf[ni] = *(const s16x8*)&lB[r * 64 + (kb ^ ((r & 7) << 3))];
      }
#pragma unroll
      for (int mi = 0; mi < 4; mi++)
#pragma unroll
        for (int ni = 0; ni < 4; ni++)
          acc[mi][ni] = __builtin_amdgcn_mfma_f32_16x16x32_bf16(af[mi], bf[ni], acc[mi][ni], 0, 0, 0);
    }
  }

  // cooperative S = sum_e Se for this block's 128 rows (LDS reuse of lA)
  __syncthreads();
  float* sS = (float*)lA;
  if (tid < 128) {
    const int bb = row0 >> 12, tt = (row0 & (T_ - 1)) + tid;
    float s = 0.f;
#pragma unroll
    for (int e = 0; e < E_; e++)
      s += Se[((size_t)(bb * E_ + e) << 12) + tt];
    sS[tid] = s;
  }
  __syncthreads();

  float bia[4];
#pragma unroll
  for (int ni = 0; ni < 4; ni++) bia[ni] = bias[col0 + wn * 64 + ni * 16 + lr];
#pragma unroll
  for (int mi = 0; mi < 4; mi++)
#pragma unroll
    for (int r = 0; r < 4; r++) {
      const int rl = wm * 64 + mi * 16 + g * 4 + r;     // local row
      const int tg = row0 + rl;
      const float s = sS[rl];
#pragma unroll
      for (int ni = 0; ni < 4; ni++) {
        const int og = col0 + wn * 64 + ni * 16 + lr;
        out[(size_t)tg * O_ + og] = acc[mi][ni][r] + bia[ni] * s;
      }
    }
}

// ---------------------------------------------------------------------------
extern "C" void kernel_launch(void* const* d_in, const int* in_sizes, int n_in,
                              void* d_out, int out_size, void* d_ws, size_t ws_size,
                              hipStream_t stream) {
  const float* x    = (const float*)d_in[0];
  const float* comb = (const float*)d_in[1];
  const float* disp = (const float*)d_in[2];
  const float* w    = (const float*)d_in[3];
  const float* bias = (const float*)d_in[4];
  float* out = (float*)d_out;

  char* ws = (char*)d_ws;
  short* wT  = (short*)(ws);                    //  8,388,608 B  [O][D] bf16 (pre-swizzled)
  short* xdT = (short*)(ws + 8388608);          //  8,388,608 B  [B,E][I][C] bf16
  short* z   = (short*)(ws + 16777216);         // 67,108,864 B  [B][T][D] bf16 (pre-swizzled)
  float* xdP = (float*)(ws + 16777216);         // 33,554,432 B  2x split-K partials (aliases z; dead before zgemm)
  float* Se  = (float*)(ws + 83886080);         //    524,288 B  [B][E][T] f32

  k_gemm1<<<dim3(1280), dim3(512), 0, stream>>>(x, disp, w, wT, xdP);
  k_cvt<<<dim3(4096), dim3(256), 0, stream>>>(xdP, xdT);
  k_zgemm<<<dim3(1024), dim3(512), 0, stream>>>(comb, xdT, z, Se);
  k_outgemm<<<dim3(1024), dim3(512), 0, stream>>>(z, wT, bias, Se, out);
}